// Round 4
// baseline (104.734 us; speedup 1.0000x reference)
//
#include <hip/hip_runtime.h>
#include <math.h>

// Problem constants (B=16, T=2048, D=1024, K=8)
#define BT   32768   // B*T rows
#define DD   1024    // D
#define DV   256     // float4 per row (D/4)
#define KC   8       // clusters
#define NPART 512    // k1 grid = number of partial-sum rows

// clang native vector type — required by __builtin_nontemporal_store
// (HIP's float4 is a class and is rejected by the builtin).
typedef float fv4 __attribute__((ext_vector_type(4)));

// ---------------------------------------------------------------------------
// Kernel 1: partial column sums of x (BT x DD). Thread t owns float4-column t.
// 8-deep explicit load batching keeps 8 float4 loads in flight per thread.
// Each block writes its partial sums NON-atomically to part[bid][1024]:
// no memset node in the graph (round-3's 32KB fillBufferAligned showed
// 77us in the counter pass), no atomic contention tail.
// ---------------------------------------------------------------------------
__global__ __launch_bounds__(256) void k1_colsum(const float* __restrict__ x,
                                                 float* __restrict__ part,
                                                 int rows_per_blk) {
    const int tid = threadIdx.x;
    const fv4* xv = (const fv4*)x;
    const long row0 = (long)blockIdx.x * rows_per_blk;
    fv4 acc = (fv4)(0.f);

    for (int r = 0; r < rows_per_blk; r += 8) {
        fv4 v[8];
#pragma unroll
        for (int i = 0; i < 8; ++i)
            v[i] = xv[(row0 + r + i) * DV + tid];
#pragma unroll
        for (int i = 0; i < 8; ++i) acc += v[i];
    }

    ((fv4*)part)[(long)blockIdx.x * DV + tid] = acc;   // plain coalesced store
}

// ---------------------------------------------------------------------------
// Kernel 2: fold the NPART partial rows (2 MB, L2-resident) -> x_mean ->
// RMS distances to the K cluster means -> softmax responsibilities r[0..K-1].
// Single block; 8-deep batched reads to cover L2 latency.
// ---------------------------------------------------------------------------
__global__ __launch_bounds__(256) void k2_resp(const float* __restrict__ part,
                                               const float* __restrict__ mus,
                                               const float* __restrict__ ws,
                                               float* __restrict__ r_out) {
    const int tid = threadIdx.x;
    const float inv_bt = 1.0f / (float)BT;

    fv4 s = (fv4)(0.f);
    for (int rep = 0; rep < NPART; rep += 8) {
        fv4 v[8];
#pragma unroll
        for (int i = 0; i < 8; ++i)
            v[i] = ((const fv4*)part)[(rep + i) * DV + tid];
#pragma unroll
        for (int i = 0; i < 8; ++i) s += v[i];
    }
    float m[4] = { s.x * inv_bt, s.y * inv_bt, s.z * inv_bt, s.w * inv_bt };

    float prt[KC];
#pragma unroll
    for (int k = 0; k < KC; ++k) {
        fv4 mu = ((const fv4*)mus)[k * DV + tid];
        float d0 = m[0] - mu.x, d1 = m[1] - mu.y;
        float d2 = m[2] - mu.z, d3 = m[3] - mu.w;
        prt[k] = d0 * d0 + d1 * d1 + d2 * d2 + d3 * d3;
    }

    __shared__ float lds[KC][4];
    const int lane = tid & 63, wv = tid >> 6;
#pragma unroll
    for (int k = 0; k < KC; ++k) {
        float v = prt[k];
#pragma unroll
        for (int off = 32; off > 0; off >>= 1) v += __shfl_down(v, off, 64);
        if (lane == 0) lds[k][wv] = v;
    }
    __syncthreads();
    if (tid == 0) {
        float logits[KC], mx = -1e30f;
#pragma unroll
        for (int k = 0; k < KC; ++k) {
            float tot = lds[k][0] + lds[k][1] + lds[k][2] + lds[k][3];
            float dist = sqrtf(tot * (1.0f / (float)DD));
            logits[k] = logf(ws[k]) - dist;
            mx = fmaxf(mx, logits[k]);
        }
        float se = 0.f, e[KC];
#pragma unroll
        for (int k = 0; k < KC; ++k) { e[k] = expf(logits[k] - mx); se += e[k]; }
        float is = 1.f / se;
#pragma unroll
        for (int k = 0; k < KC; ++k) r_out[k] = e[k] * is;
    }
}

// ---------------------------------------------------------------------------
// Kernel 3: main elementwise pass. Thread's scalar columns are fixed
// (tid*4 .. tid*4+3), so tau*log2(e), alpha, mu[k][e], r[k] live in registers
// across all row iterations. Non-temporal store keeps x resident in the
// Infinity Cache (x + out = 268 MB > 256 MB L3 otherwise thrashes).
// ---------------------------------------------------------------------------
__global__ __launch_bounds__(256) void k3_main(const float* __restrict__ x,
                                               const float* __restrict__ mus,
                                               const float* __restrict__ log_tau,
                                               const float* __restrict__ log_blend,
                                               const float* __restrict__ rbuf,
                                               float* __restrict__ out,
                                               int rows_per_blk) {
    const int tid = threadIdx.x;
    const float LOG2E = 1.44269504f;

    fv4 lt = ((const fv4*)log_tau)[tid];
    fv4 lb = ((const fv4*)log_blend)[tid];
    float tl[4], al[4];
    tl[0] = __builtin_amdgcn_exp2f(lt.x * LOG2E) * LOG2E;
    tl[1] = __builtin_amdgcn_exp2f(lt.y * LOG2E) * LOG2E;
    tl[2] = __builtin_amdgcn_exp2f(lt.z * LOG2E) * LOG2E;
    tl[3] = __builtin_amdgcn_exp2f(lt.w * LOG2E) * LOG2E;
    al[0] = 1.f / (1.f + __builtin_amdgcn_exp2f(-lb.x * LOG2E));
    al[1] = 1.f / (1.f + __builtin_amdgcn_exp2f(-lb.y * LOG2E));
    al[2] = 1.f / (1.f + __builtin_amdgcn_exp2f(-lb.z * LOG2E));
    al[3] = 1.f / (1.f + __builtin_amdgcn_exp2f(-lb.w * LOG2E));

    float mu[KC][4];
#pragma unroll
    for (int k = 0; k < KC; ++k) {
        fv4 m4 = ((const fv4*)mus)[k * DV + tid];
        mu[k][0] = m4.x; mu[k][1] = m4.y; mu[k][2] = m4.z; mu[k][3] = m4.w;
    }
    float rk[KC];
#pragma unroll
    for (int k = 0; k < KC; ++k) rk[k] = rbuf[k];

    const fv4* xv = (const fv4*)x;
    fv4* ov = (fv4*)out;
    const long row0 = (long)blockIdx.x * rows_per_blk;

    for (int rr = 0; rr < rows_per_blk; ++rr) {
        const long idx = (row0 + rr) * DV + tid;
        fv4 v = xv[idx];
        float xin[4] = { v.x, v.y, v.z, v.w };
        float o[4];
#pragma unroll
        for (int e = 0; e < 4; ++e) {
            float xe = xin[e];
            float fam = 0.f;
#pragma unroll
            for (int k = 0; k < KC; ++k) {
                fam += rk[k] * __builtin_amdgcn_exp2f(-tl[e] * fabsf(xe - mu[k][e]));
            }
            float y = xe * (1.f - al[e] * fam);
            float z = 0.79788456f * (y + 0.044715f * y * y * y);
            float e2 = __builtin_amdgcn_exp2f(2.88539008f * z);
            float th = 1.f - 2.f * __builtin_amdgcn_rcpf(e2 + 1.f);
            o[e] = 0.5f * y * (1.f + th);
        }
        fv4 res; res.x = o[0]; res.y = o[1]; res.z = o[2]; res.w = o[3];
        __builtin_nontemporal_store(res, &ov[idx]);
    }
}

extern "C" void kernel_launch(void* const* d_in, const int* in_sizes, int n_in,
                              void* d_out, int out_size, void* d_ws, size_t ws_size,
                              hipStream_t stream) {
    const float* x         = (const float*)d_in[0];
    const float* mus       = (const float*)d_in[1];
    const float* ws        = (const float*)d_in[2];
    const float* log_tau   = (const float*)d_in[3];
    const float* log_blend = (const float*)d_in[4];
    float* out = (float*)d_out;

    float* part = (float*)d_ws;            // NPART * DD floats (2 MB)
    float* rbuf = part + (long)NPART * DD; // KC floats

    const int g1 = NPART;                  // 64 rows per block
    k1_colsum<<<g1, 256, 0, stream>>>(x, part, BT / g1);

    k2_resp<<<1, 256, 0, stream>>>(part, mus, ws, rbuf);

    const int g3 = 2048;                   // 16 rows per block
    k3_main<<<g3, 256, 0, stream>>>(x, mus, log_tau, log_blend, rbuf, out, BT / g3);
}